// Round 9
// baseline (1119.832 us; speedup 1.0000x reference)
//
#include <hip/hip_runtime.h>
#include <stdint.h>

#define HNUM 240
#define WNUM 1216
#define BNUM 4
#define HWN (HNUM * WNUM)
#define NPIX (BNUM * HWN)
#define WP (WNUM + 3)
#define HP (HNUM + 3)
#define PLANE (HP * WP)
#define PP ((PLANE + 15) & ~15)      /* even per-batch pitch (296224) */
#define NPP (BNUM * PP)
#define PXT 10
#define NTHR (NPIX / PXT)            /* 116736 */
#define NBLK (NTHR / 256)            /* 456 = 8 * 57 */
#define XCHUNK (NBLK / 8)            /* 57 */
#define WAVEPX (64 * PXT)            /* 640; HWN/640 = 456 exact */
#define NBORD (3 * WP + 3 * HNUM + (PP - PLANE))   /* 4384 */
#define SYNC_STRIDE 32               /* dwords between counters = 128 B */
#define NSYNC 6

union HCV { uint32_t u; _Float16 h[2]; };

__device__ __forceinline__ float fast_tanh(float x) {
    float ax = fabsf(x);
    float e  = __builtin_amdgcn_exp2f(ax * 2.885390081777927f);  // 2*log2(e)
    float t  = 1.0f - 2.0f * __builtin_amdgcn_rcpf(e + 1.0f);
    return copysignf(t, x);
}

__device__ __forceinline__ float h2lo(uint32_t u) { HCV c; c.u = u; return (float)c.h[0]; }
__device__ __forceinline__ float h2hi(uint32_t u) { HCV c; c.u = u; return (float)c.h[1]; }

// hand-rolled inline grid barrier: no function call -> no ABI spill.
__device__ __forceinline__ void grid_barrier(uint32_t* syncc, int ph) {
    __syncthreads();
    if (threadIdx.x == 0) {
        uint32_t* c = syncc + ph * SYNC_STRIDE;
        __hip_atomic_fetch_add(c, 1u, __ATOMIC_ACQ_REL, __HIP_MEMORY_SCOPE_AGENT);
        while (__hip_atomic_load(c, __ATOMIC_RELAXED, __HIP_MEMORY_SCOPE_AGENT)
               < (uint32_t)NBLK) {
            __builtin_amdgcn_s_sleep(2);
        }
        (void)__hip_atomic_load(c, __ATOMIC_ACQUIRE, __HIP_MEMORY_SCOPE_AGENT);
    }
    __syncthreads();
}

// dual-plane bilinear tap: pEv = dword view of natural plane, pOd = +1-shifted.
__device__ __forceinline__ void tap_dual(uint32_t m, float a,
                                         const uint32_t* __restrict__ pEv,
                                         const uint32_t* __restrict__ pOd,
                                         int afp, float& acc) {
    int   rel = (int)(int16_t)(m & 0xffffu);
    float wy  = (float)((m >> 16) & 0xffu) * (1.0f / 255.0f);
    float wx  = (float)(m >> 24)           * (1.0f / 255.0f);
    int a0 = afp + rel;
    int a1 = a0 + WP;
    const uint32_t* r0 = (a0 & 1) ? pOd : pEv;
    const uint32_t* r1 = (a0 & 1) ? pEv : pOd;
    HCV c0, c1;
    c0.u = r0[a0 >> 1];   // (g00, g01)
    c1.u = r1[a1 >> 1];   // (g10, g11)
    float g00 = (float)c0.h[0], g01 = (float)c0.h[1];
    float g10 = (float)c1.h[0], g11 = (float)c1.h[1];
    float top = fmaf(wx, g01 - g00, g00);
    float bot = fmaf(wx, g11 - g10, g10);
    acc = fmaf(a, fmaf(wy, bot - top, top), acc);
}

__device__ __forceinline__ uint32_t build_tap(int h, int w, int dy, int dx,
                                              float offy, float offx, float& a) {
    float ys  = (float)(h + dy) + offy;
    float xs  = (float)(w + dx) + offx;
    float y0f = floorf(ys), x0f = floorf(xs);
    int   y0  = (int)y0f,  x0  = (int)x0f;
    float wy  = ys - y0f,  wx  = xs - x0f;
    uint32_t qy = (uint32_t)(wy * 255.0f + 0.5f); if (qy > 255) qy = 255;
    uint32_t qx = (uint32_t)(wx * 255.0f + 0.5f); if (qx > 255) qx = 255;
    bool valid = (y0 >= -1) & (y0 <= HNUM) & (x0 >= -1) & (x0 <= WNUM);
    int rel = (y0 - h) * WP + (x0 - w);
    if (!valid || rel < -32768 || rel > 32767) { rel = 0; qy = 0; qx = 0; a = 0.f; }
    return (uint32_t)(uint16_t)(int16_t)rel | (qy << 16) | (qx << 24);
}

// per-pixel persistent meta: 16 dwords, all named members
struct Px {
    uint32_t t0, t1, t2, t3, t4, t5, t6, t7;   // packed taps
    uint32_t a01, a23, a45, a67;               // affs as fp16 pairs
    uint32_t ac;                               // (aref fp16) | (conf fp16 << 16)
    float    dp;                               // dep
    int      bp;                               // plane cell index (batch-local)
};

__device__ __forceinline__ void build_px(
    Px& M, int j, int hwb, int pxb, int b, float invs,
    const float* __restrict__ arb, const float* __restrict__ ofb,
    const float* __restrict__ conf, const float* __restrict__ dep,
    const float* __restrict__ pred,
    _Float16* __restrict__ A0, _Float16* __restrict__ A1)
{
    int hw = hwb + 64 * j;
    int h  = hw / WNUM;
    int w  = hw - h * WNUM;
    int bp = (h + 1) * WP + (w + 1);
    M.bp = bp;

    float aa[8];
    float asum = 0.f;
#pragma unroll
    for (int k = 0; k < 8; ++k) {
        float t = fast_tanh(arb[(size_t)k * HWN + hw]) * invs;
        aa[k] = t;
        asum += fabsf(t);
    }
    float rden = 1.0f / fmaxf(asum + 1e-4f, 1.0f);
    float sm = 0.f;
#pragma unroll
    for (int k = 0; k < 8; ++k) { aa[k] *= rden; sm += aa[k]; }
    float aref = 1.0f - sm;

    uint32_t tw[8];
#pragma unroll
    for (int k = 0; k < 8; ++k) {
        int k9 = (k < 4) ? k : k + 1;
        int dy = k9 / 3 - 1;
        int dx = k9 - (k9 / 3) * 3 - 1;
        float offy = ofb[(size_t)(2 * k)     * HWN + hw];
        float offx = ofb[(size_t)(2 * k + 1) * HWN + hw];
        tw[k] = build_tap(h, w, dy, dx, offy, offx, aa[k]);
    }
    M.t0 = tw[0]; M.t1 = tw[1]; M.t2 = tw[2]; M.t3 = tw[3];
    M.t4 = tw[4]; M.t5 = tw[5]; M.t6 = tw[6]; M.t7 = tw[7];

    HCV cv;
    cv.h[0] = (_Float16)aa[0]; cv.h[1] = (_Float16)aa[1]; M.a01 = cv.u;
    cv.h[0] = (_Float16)aa[2]; cv.h[1] = (_Float16)aa[3]; M.a23 = cv.u;
    cv.h[0] = (_Float16)aa[4]; cv.h[1] = (_Float16)aa[5]; M.a45 = cv.u;
    cv.h[0] = (_Float16)aa[6]; cv.h[1] = (_Float16)aa[7]; M.a67 = cv.u;

    int   gp = pxb + 64 * j;
    float cf = conf[gp];
    float dd = dep[gp];
    float pp = pred[gp];
    cv.h[0] = (_Float16)aref; cv.h[1] = (_Float16)cf; M.ac = cv.u;
    M.dp = dd;

    _Float16 o = (_Float16)(pp * cf);
    size_t gb = (size_t)b * PP + bp;
    A0[gb]     = o;
    A1[gb - 1] = o;
}

__device__ __forceinline__ void step_px(
    const Px& M, int j, int pxb, bool last,
    const _Float16* __restrict__ I0b,
    const uint32_t* __restrict__ pEv, const uint32_t* __restrict__ pOd,
    _Float16* __restrict__ O0b, _Float16* __restrict__ O1b,
    float* __restrict__ out)
{
    int bp = M.bp;
    float aref = h2lo(M.ac);
    float cf   = h2hi(M.ac);
    float acc  = aref * (float)I0b[bp];
    tap_dual(M.t0, h2lo(M.a01), pEv, pOd, bp, acc);
    tap_dual(M.t1, h2hi(M.a01), pEv, pOd, bp, acc);
    tap_dual(M.t2, h2lo(M.a23), pEv, pOd, bp, acc);
    tap_dual(M.t3, h2hi(M.a23), pEv, pOd, bp, acc);
    tap_dual(M.t4, h2lo(M.a45), pEv, pOd, bp, acc);
    tap_dual(M.t5, h2hi(M.a45), pEv, pOd, bp, acc);
    tap_dual(M.t6, h2lo(M.a67), pEv, pOd, bp, acc);
    tap_dual(M.t7, h2hi(M.a67), pEv, pOd, bp, acc);
    float dd   = M.dp;
    float feat = (dd > 0.f) ? dd : acc;
    if (last) {
        out[pxb + 64 * j] = feat;
    } else {
        _Float16 o = (_Float16)(feat * cf);
        O0b[bp]     = o;
        O1b[bp - 1] = o;
    }
}

// ---------------------------------------------------------------------------
// persistent fused kernel: meta in registers, 6 steps, inline grid barrier
// ---------------------------------------------------------------------------
__global__ __launch_bounds__(256, 2) void nlspn_fused(
    const float* __restrict__ aff_raw,
    const float* __restrict__ offset,
    const float* __restrict__ conf,
    const float* __restrict__ pred,
    const float* __restrict__ dep,
    const float* __restrict__ scale,
    _Float16* __restrict__ A0, _Float16* __restrict__ A1,
    _Float16* __restrict__ B0, _Float16* __restrict__ B1,
    uint32_t* __restrict__ syncc,
    float* __restrict__ out)
{
    int bid = blockIdx.x;
    int nb  = (bid & 7) * XCHUNK + (bid >> 3);         // bijective: 456 = 8*57
    int tid = nb * 256 + (int)threadIdx.x;             // < NTHR exactly
    int l   = tid & 63;
    int wv  = tid >> 6;
    int pxb = wv * WAVEPX + l;                         // lane's first px
    int b   = pxb / HWN;                               // uniform per wave
    int hwb = pxb - b * HWN;

    // ---- zero plane borders + pads (disjoint from interiors) ----
    if (tid < BNUM * NBORD) {
        int bb  = tid / NBORD;
        int idx = tid - bb * NBORD;
        int cell;
        if (idx < 3 * WP) {
            int r3 = idx / WP;
            int c  = idx - r3 * WP;
            int ph = (r3 == 0) ? 0 : (240 + r3);       // rows 0, 241, 242
            cell = ph * WP + c;
        } else if (idx < 3 * WP + 3 * HNUM) {
            int i2 = idx - 3 * WP;
            int r  = i2 / 3;
            int c3 = i2 - r * 3;
            int c  = (c3 == 0) ? 0 : (WNUM + c3);      // cols 0, 1217, 1218
            cell = (1 + r) * WP + c;
        } else {
            cell = PLANE + (idx - (3 * WP + 3 * HNUM));   // pads PLANE..PP
        }
        size_t base = (size_t)bb * PP;
        if (cell < PP) {
            A0[base + cell] = (_Float16)0.f;
            B0[base + cell] = (_Float16)0.f;
        }
        if (cell >= 1) {
            A1[base + cell - 1] = (_Float16)0.f;
            B1[base + cell - 1] = (_Float16)0.f;
        }
    }

    float s    = scale[0];
    float invs = 1.0f / (s + 1e-8f);

    const float* arb = aff_raw + (size_t)b * 8 * HWN;
    const float* ofb = offset  + (size_t)b * 16 * HWN;

    Px m0, m1, m2, m3, m4, m5, m6, m7, m8, m9;

    build_px(m0, 0, hwb, pxb, b, invs, arb, ofb, conf, dep, pred, A0, A1);
    __builtin_amdgcn_sched_barrier(0);
    build_px(m1, 1, hwb, pxb, b, invs, arb, ofb, conf, dep, pred, A0, A1);
    __builtin_amdgcn_sched_barrier(0);
    build_px(m2, 2, hwb, pxb, b, invs, arb, ofb, conf, dep, pred, A0, A1);
    __builtin_amdgcn_sched_barrier(0);
    build_px(m3, 3, hwb, pxb, b, invs, arb, ofb, conf, dep, pred, A0, A1);
    __builtin_amdgcn_sched_barrier(0);
    build_px(m4, 4, hwb, pxb, b, invs, arb, ofb, conf, dep, pred, A0, A1);
    __builtin_amdgcn_sched_barrier(0);
    build_px(m5, 5, hwb, pxb, b, invs, arb, ofb, conf, dep, pred, A0, A1);
    __builtin_amdgcn_sched_barrier(0);
    build_px(m6, 6, hwb, pxb, b, invs, arb, ofb, conf, dep, pred, A0, A1);
    __builtin_amdgcn_sched_barrier(0);
    build_px(m7, 7, hwb, pxb, b, invs, arb, ofb, conf, dep, pred, A0, A1);
    __builtin_amdgcn_sched_barrier(0);
    build_px(m8, 8, hwb, pxb, b, invs, arb, ofb, conf, dep, pred, A0, A1);
    __builtin_amdgcn_sched_barrier(0);
    build_px(m9, 9, hwb, pxb, b, invs, arb, ofb, conf, dep, pred, A0, A1);
    __builtin_amdgcn_sched_barrier(0);

    grid_barrier(syncc, 0);

    _Float16 *I0 = A0, *I1 = A1, *O0 = B0, *O1 = B1;
#pragma unroll 1
    for (int st = 0; st < 6; ++st) {
        bool last = (st == 5);
        const _Float16* I0b = I0 + (size_t)b * PP;
        const uint32_t* pEv = (const uint32_t*)I0b;
        const uint32_t* pOd = (const uint32_t*)(I1 + (size_t)b * PP);
        _Float16* O0b = O0 + (size_t)b * PP;
        _Float16* O1b = O1 + (size_t)b * PP;

        step_px(m0, 0, pxb, last, I0b, pEv, pOd, O0b, O1b, out);
        step_px(m1, 1, pxb, last, I0b, pEv, pOd, O0b, O1b, out);
        __builtin_amdgcn_sched_barrier(0);
        step_px(m2, 2, pxb, last, I0b, pEv, pOd, O0b, O1b, out);
        step_px(m3, 3, pxb, last, I0b, pEv, pOd, O0b, O1b, out);
        __builtin_amdgcn_sched_barrier(0);
        step_px(m4, 4, pxb, last, I0b, pEv, pOd, O0b, O1b, out);
        step_px(m5, 5, pxb, last, I0b, pEv, pOd, O0b, O1b, out);
        __builtin_amdgcn_sched_barrier(0);
        step_px(m6, 6, pxb, last, I0b, pEv, pOd, O0b, O1b, out);
        step_px(m7, 7, pxb, last, I0b, pEv, pOd, O0b, O1b, out);
        __builtin_amdgcn_sched_barrier(0);
        step_px(m8, 8, pxb, last, I0b, pEv, pOd, O0b, O1b, out);
        step_px(m9, 9, pxb, last, I0b, pEv, pOd, O0b, O1b, out);

        if (st < 5) grid_barrier(syncc, st + 1);
        _Float16* t;
        t = I0; I0 = O0; O0 = t;
        t = I1; I1 = O1; O1 = t;
    }
}

// ---------------------------------------------------------------------------
// fallback (round-1 style) if cooperative launch unavailable
// ---------------------------------------------------------------------------
__global__ __launch_bounds__(256) void nlspn_init_kernel(
    const float* __restrict__ pred,
    const float* __restrict__ conf,
    float* __restrict__ ff)
{
    int p = blockIdx.x * blockDim.x + threadIdx.x;
    if (p < NPIX) ff[p] = pred[p] * conf[p];
}

template <bool LAST>
__global__ __launch_bounds__(256) void nlspn_prop_kernel(
    const float* __restrict__ aff_raw,
    const float* __restrict__ offset,
    const float* __restrict__ conf,
    const float* __restrict__ dep,
    const float* __restrict__ scale,
    const float* __restrict__ ff_in,
    float* __restrict__ out)
{
    int p = blockIdx.x * blockDim.x + threadIdx.x;
    if (p >= NPIX) return;
    int b  = p / HWN;
    int hw = p - b * HWN;
    int h  = hw / WNUM;
    int w  = hw - h * WNUM;

    float s    = scale[0];
    float invs = 1.0f / (s + 1e-8f);

    float a[8];
    const float* ar = aff_raw + (size_t)b * 8 * HWN + hw;
#pragma unroll
    for (int k = 0; k < 8; ++k) a[k] = ar[(size_t)k * HWN];

    float asum = 0.0f;
#pragma unroll
    for (int k = 0; k < 8; ++k) {
        a[k] = fast_tanh(a[k]) * invs;
        asum += fabsf(a[k]);
    }
    asum += 1e-4f;
    float rden = 1.0f / fmaxf(asum, 1.0f);
    float suma = 0.0f;
#pragma unroll
    for (int k = 0; k < 8; ++k) { a[k] *= rden; suma += a[k]; }
    float aref = 1.0f - suma;

    const float* ffb = ff_in + (size_t)b * HWN;
    float acc = aref * ffb[hw];

    const float* off = offset + (size_t)b * 16 * HWN + hw;
#pragma unroll
    for (int k = 0; k < 8; ++k) {
        int   k9 = (k < 4) ? k : k + 1;
        int   dy = k9 / 3 - 1;
        int   dx = k9 - (k9 / 3) * 3 - 1;
        float offy = off[(size_t)(2 * k)     * HWN];
        float offx = off[(size_t)(2 * k + 1) * HWN];
        float ysf = (float)(h + dy) + offy;
        float xsf = (float)(w + dx) + offx;
        float y0f = floorf(ysf);
        float x0f = floorf(xsf);
        float wy  = ysf - y0f;
        float wx  = xsf - x0f;
        int   y0  = (int)y0f;
        int   x0  = (int)x0f;
        bool yv0 = (y0 >= 0)  & (y0 < HNUM);
        bool yv1 = (y0 >= -1) & (y0 + 1 < HNUM);
        bool xv0 = (x0 >= 0)  & (x0 < WNUM);
        bool xv1 = (x0 >= -1) & (x0 + 1 < WNUM);
        int row0 = y0 * WNUM;
        float g00 = 0.f, g01 = 0.f, g10 = 0.f, g11 = 0.f;
        if (yv0 & xv0) g00 = ffb[row0 + x0];
        if (yv0 & xv1) g01 = ffb[row0 + x0 + 1];
        if (yv1 & xv0) g10 = ffb[row0 + WNUM + x0];
        if (yv1 & xv1) g11 = ffb[row0 + WNUM + x0 + 1];
        float sampled = (1.f - wy) * ((1.f - wx) * g00 + wx * g01)
                      +        wy  * ((1.f - wx) * g10 + wx * g11);
        acc += a[k] * sampled;
    }

    float dd   = dep[p];
    float feat = (dd > 0.0f) ? dd : acc;
    if (LAST) out[p] = feat;
    else      out[p] = feat * conf[p];
}

// ---------------------------------------------------------------------------
extern "C" void kernel_launch(void* const* d_in, const int* in_sizes, int n_in,
                              void* d_out, int out_size, void* d_ws, size_t ws_size,
                              hipStream_t stream)
{
    const float* aff_raw = (const float*)d_in[0];
    const float* offset  = (const float*)d_in[1];
    const float* conf    = (const float*)d_in[2];
    const float* pred    = (const float*)d_in[3];
    const float* dep     = (const float*)d_in[4];
    const float* scale   = (const float*)d_in[5];
    float* out = (float*)d_out;

    const size_t planeBytes = (size_t)NPP * 2;
    const size_t syncBytes  = (size_t)NSYNC * SYNC_STRIDE * 4;
    bool launched = false;

    if (ws_size >= 4 * planeBytes + syncBytes + 256) {
        char* wb = (char*)d_ws;
        _Float16* A0 = (_Float16*)wb;  wb += planeBytes;
        _Float16* A1 = (_Float16*)wb;  wb += planeBytes;
        _Float16* B0 = (_Float16*)wb;  wb += planeBytes;
        _Float16* B1 = (_Float16*)wb;  wb += planeBytes;
        uint32_t* syncc = (uint32_t*)wb;

        hipMemsetAsync((void*)syncc, 0, syncBytes, stream);

        void* args[] = {
            (void*)&aff_raw, (void*)&offset, (void*)&conf, (void*)&pred,
            (void*)&dep, (void*)&scale,
            (void*)&A0, (void*)&A1, (void*)&B0, (void*)&B1,
            (void*)&syncc, (void*)&out
        };
        hipError_t err = hipLaunchCooperativeKernel(
            (const void*)nlspn_fused, dim3(NBLK), dim3(256), args, 0, stream);
        if (err == hipSuccess) {
            launched = true;
        } else {
            (void)hipGetLastError();   // clear sticky error, take fallback
        }
    }

    if (!launched) {
        const int threads = 256;
        const int blocksP = (NPIX + threads - 1) / threads;
        float* ws = (float*)d_ws;
        nlspn_init_kernel<<<blocksP, threads, 0, stream>>>(pred, conf, out);
        nlspn_prop_kernel<false><<<blocksP, threads, 0, stream>>>(aff_raw, offset, conf, dep, scale, out, ws);
        nlspn_prop_kernel<false><<<blocksP, threads, 0, stream>>>(aff_raw, offset, conf, dep, scale, ws, out);
        nlspn_prop_kernel<false><<<blocksP, threads, 0, stream>>>(aff_raw, offset, conf, dep, scale, out, ws);
        nlspn_prop_kernel<false><<<blocksP, threads, 0, stream>>>(aff_raw, offset, conf, dep, scale, ws, out);
        nlspn_prop_kernel<false><<<blocksP, threads, 0, stream>>>(aff_raw, offset, conf, dep, scale, out, ws);
        nlspn_prop_kernel<true ><<<blocksP, threads, 0, stream>>>(aff_raw, offset, conf, dep, scale, ws, out);
    }
}

// Round 10
// 155.068 us; speedup vs baseline: 7.2216x; 7.2216x over previous
//
#include <hip/hip_runtime.h>
#include <stdint.h>

#define HNUM 240
#define WNUM 1216
#define BNUM 4
#define HWN (HNUM * WNUM)
#define NPIX (BNUM * HWN)
#define WP (WNUM + 3)
#define HP (HNUM + 3)
#define PLANE (HP * WP)
#define PP ((PLANE + 15) & ~15)      /* even per-batch pitch */
#define NPP (BNUM * PP)
#define GRIDP (NPIX / 256)           /* 4560 = 8 * 570 */
#define CHUNKP (GRIDP / 8)           /* 570 */

union HCV { uint32_t u; _Float16 h[2]; };

__device__ __forceinline__ float fast_tanh(float x) {
    float ax = fabsf(x);
    float e  = __builtin_amdgcn_exp2f(ax * 2.885390081777927f);  // 2*log2(e)
    float t  = 1.0f - 2.0f * __builtin_amdgcn_rcpf(e + 1.0f);
    return copysignf(t, x);
}

__device__ __forceinline__ uint32_t build_tap(int h, int w, int dy, int dx,
                                              float offy, float offx, float& a) {
    float ys  = (float)(h + dy) + offy;
    float xs  = (float)(w + dx) + offx;
    float y0f = floorf(ys), x0f = floorf(xs);
    int   y0  = (int)y0f,  x0  = (int)x0f;
    float wy  = ys - y0f,  wx  = xs - x0f;
    uint32_t qy = (uint32_t)(wy * 255.0f + 0.5f); if (qy > 255) qy = 255;
    uint32_t qx = (uint32_t)(wx * 255.0f + 0.5f); if (qx > 255) qx = 255;
    bool valid = (y0 >= -1) & (y0 <= HNUM) & (x0 >= -1) & (x0 <= WNUM);
    int rel = (y0 - h) * WP + (x0 - w);
    if (!valid || rel < -32768 || rel > 32767) { rel = 0; qy = 0; qx = 0; a = 0.f; }
    return (uint32_t)(uint16_t)(int16_t)rel | (qy << 16) | (qx << 24);
}

// ---------------------------------------------------------------------------
// init: A0 = padded pred*conf plane, A1 = same shifted by one fp16; B zeroed.
// ---------------------------------------------------------------------------
__device__ __forceinline__ float cellval(const float* __restrict__ pred,
                                         const float* __restrict__ conf,
                                         int b, int c) {
    int ph = c / WP;
    int pw = c - ph * WP;
    int h = ph - 1, w = pw - 1;
    if (h < 0 || h >= HNUM || w < 0 || w >= WNUM) return 0.f;
    int p = b * HWN + h * WNUM + w;
    return pred[p] * conf[p];
}

__global__ __launch_bounds__(256) void nlspn_init_dual(
    const float* __restrict__ pred,
    const float* __restrict__ conf,
    _Float16* __restrict__ A0,
    _Float16* __restrict__ A1,
    _Float16* __restrict__ B0,
    _Float16* __restrict__ B1)
{
    int i = blockIdx.x * blockDim.x + threadIdx.x;
    if (i >= NPP) return;
    int b = i / PP;
    int c = i - b * PP;
    A0[i] = (_Float16)cellval(pred, conf, b, c);
    A1[i] = (_Float16)((c + 1 < PP) ? cellval(pred, conf, b, c + 1) : 0.f);
    B0[i] = (_Float16)0.f;
    B1[i] = (_Float16)0.f;
}

// ---------------------------------------------------------------------------
// step 1 fused with meta build. 1 px/thread, phase-split for MLP:
//   A: issue ALL 26 input loads  B: affinity math  C: taps
//   D: issue ALL 17 gather loads E: accumulate     F: stores
// ---------------------------------------------------------------------------
__global__ __launch_bounds__(256, 4) void nlspn_step1_build(
    const float* __restrict__ aff_raw,
    const float* __restrict__ offset,
    const float* __restrict__ conf,
    const float* __restrict__ dep,
    const float* __restrict__ scale,
    const _Float16* __restrict__ A0,
    const _Float16* __restrict__ A1,
    _Float16* __restrict__ B0,
    _Float16* __restrict__ B1,
    uint4* __restrict__ tapsA,
    uint4* __restrict__ tapsB,
    uint4* __restrict__ affv,
    uint2* __restrict__ auxv)
{
    int bid = blockIdx.x;
    int nb  = (bid & 7) * CHUNKP + (bid >> 3);     // bijective: 4560 = 8*570
    int p   = nb * 256 + (int)threadIdx.x;         // < NPIX exactly
    int b  = p / HWN;
    int hw = p - b * HWN;
    int h  = hw / WNUM;
    int w  = hw - h * WNUM;
    int bp = (h + 1) * WP + (w + 1);

    float s    = scale[0];
    float invs = 1.0f / (s + 1e-8f);

    const float* arb = aff_raw + (size_t)b * 8 * HWN + hw;
    const float* ofb = offset  + (size_t)b * 16 * HWN + hw;

    // ---- phase A: all input loads ----
    float ar[8], oy[8], ox[8];
#pragma unroll
    for (int k = 0; k < 8; ++k) ar[k] = arb[(size_t)k * HWN];
#pragma unroll
    for (int k = 0; k < 8; ++k) {
        oy[k] = ofb[(size_t)(2 * k)     * HWN];
        ox[k] = ofb[(size_t)(2 * k + 1) * HWN];
    }
    float cf = conf[p];
    float dd = dep[p];

    // ---- phase B: affinity normalization ----
    float aa[8];
    float asum = 0.f;
#pragma unroll
    for (int k = 0; k < 8; ++k) {
        float t = fast_tanh(ar[k]) * invs;
        aa[k] = t;
        asum += fabsf(t);
    }
    float rden = 1.0f / fmaxf(asum + 1e-4f, 1.0f);
    float sm = 0.f;
#pragma unroll
    for (int k = 0; k < 8; ++k) { aa[k] *= rden; sm += aa[k]; }
    float aref = 1.0f - sm;

    // ---- phase C: build taps ----
    uint32_t tw[8];
#pragma unroll
    for (int k = 0; k < 8; ++k) {
        int k9 = (k < 4) ? k : k + 1;
        int dy = k9 / 3 - 1;
        int dx = k9 - (k9 / 3) * 3 - 1;
        tw[k] = build_tap(h, w, dy, dx, oy[k], ox[k], aa[k]);
    }

    // ---- phase D: issue all gather loads (dual plane: 2 aligned dwords/tap) ----
    const _Float16* I0b = A0 + (size_t)b * PP;
    const uint32_t* pEv = (const uint32_t*)I0b;
    const uint32_t* pOd = (const uint32_t*)(A1 + (size_t)b * PP);
    uint32_t glo[8], ghi[8];
#pragma unroll
    for (int k = 0; k < 8; ++k) {
        int rel = (int)(int16_t)(tw[k] & 0xffffu);
        int q0  = bp + rel;
        int q1  = q0 + WP;
        const uint32_t* r0 = (q0 & 1) ? pOd : pEv;
        const uint32_t* r1 = (q0 & 1) ? pEv : pOd;
        glo[k] = r0[q0 >> 1];
        ghi[k] = r1[q1 >> 1];
    }
    float ctr = (float)I0b[bp];

    // ---- phase E: accumulate ----
    float acc = aref * ctr;
#pragma unroll
    for (int k = 0; k < 8; ++k) {
        float wy = (float)((tw[k] >> 16) & 0xffu) * (1.0f / 255.0f);
        float wx = (float)(tw[k] >> 24)           * (1.0f / 255.0f);
        HCV c0, c1;
        c0.u = glo[k]; c1.u = ghi[k];
        float g00 = (float)c0.h[0], g01 = (float)c0.h[1];
        float g10 = (float)c1.h[0], g11 = (float)c1.h[1];
        float top = fmaf(wx, g01 - g00, g00);
        float bot = fmaf(wx, g11 - g10, g10);
        acc = fmaf(aa[k], fmaf(wy, bot - top, top), acc);
    }

    // ---- phase F: stores ----
    tapsA[p] = make_uint4(tw[0], tw[1], tw[2], tw[3]);
    tapsB[p] = make_uint4(tw[4], tw[5], tw[6], tw[7]);
    HCV cv;
    uint32_t aw[4];
#pragma unroll
    for (int q = 0; q < 4; ++q) {
        cv.h[0] = (_Float16)aa[2 * q];
        cv.h[1] = (_Float16)aa[2 * q + 1];
        aw[q] = cv.u;
    }
    affv[p] = make_uint4(aw[0], aw[1], aw[2], aw[3]);
    cv.h[0] = (_Float16)aref; cv.h[1] = (_Float16)cf;
    auxv[p] = make_uint2(cv.u, __float_as_uint(dd));

    float feat = (dd > 0.f) ? dd : acc;
    _Float16 o = (_Float16)(feat * cf);
    _Float16* B0b = B0 + (size_t)b * PP;
    _Float16* B1b = B1 + (size_t)b * PP;
    B0b[bp]     = o;
    B1b[bp - 1] = o;
}

// ---------------------------------------------------------------------------
// lean propagation step. 1 px/thread, phase-split:
//   A: 4 meta vector loads  B: issue all 17 gathers  C: math  D: store
// ---------------------------------------------------------------------------
template <bool LAST>
__global__ __launch_bounds__(256, 4) void nlspn_prop_dual(
    const uint4* __restrict__ tapsA,
    const uint4* __restrict__ tapsB,
    const uint4* __restrict__ affv,
    const uint2* __restrict__ auxv,
    const _Float16* __restrict__ I0,
    const _Float16* __restrict__ I1,
    _Float16* __restrict__ O0,
    _Float16* __restrict__ O1,
    float* __restrict__ out)
{
    int bid = blockIdx.x;
    int nb  = (bid & 7) * CHUNKP + (bid >> 3);     // bijective: 4560 = 8*570
    int p   = nb * 256 + (int)threadIdx.x;         // < NPIX exactly
    int b  = p / HWN;
    int hw = p - b * HWN;
    int h  = hw / WNUM;
    int w  = hw - h * WNUM;
    int bp = (h + 1) * WP + (w + 1);

    // ---- phase A: meta loads ----
    uint4 tA = tapsA[p];
    uint4 tB = tapsB[p];
    uint4 av = affv[p];
    uint2 ax = auxv[p];

    uint32_t tm[8] = {tA.x, tA.y, tA.z, tA.w, tB.x, tB.y, tB.z, tB.w};

    // ---- phase B: issue all gathers ----
    const _Float16* I0b = I0 + (size_t)b * PP;
    const uint32_t* pEv = (const uint32_t*)I0b;
    const uint32_t* pOd = (const uint32_t*)(I1 + (size_t)b * PP);
    uint32_t glo[8], ghi[8];
#pragma unroll
    for (int k = 0; k < 8; ++k) {
        int rel = (int)(int16_t)(tm[k] & 0xffffu);
        int q0  = bp + rel;
        int q1  = q0 + WP;
        const uint32_t* r0 = (q0 & 1) ? pOd : pEv;
        const uint32_t* r1 = (q0 & 1) ? pEv : pOd;
        glo[k] = r0[q0 >> 1];
        ghi[k] = r1[q1 >> 1];
    }
    float ctr = (float)I0b[bp];

    // ---- phase C: math ----
    HCV cv;
    float aff[8];
    cv.u = av.x; aff[0] = (float)cv.h[0]; aff[1] = (float)cv.h[1];
    cv.u = av.y; aff[2] = (float)cv.h[0]; aff[3] = (float)cv.h[1];
    cv.u = av.z; aff[4] = (float)cv.h[0]; aff[5] = (float)cv.h[1];
    cv.u = av.w; aff[6] = (float)cv.h[0]; aff[7] = (float)cv.h[1];
    cv.u = ax.x;
    float aref = (float)cv.h[0];
    float cf   = (float)cv.h[1];
    float dd   = __uint_as_float(ax.y);

    float acc = aref * ctr;
#pragma unroll
    for (int k = 0; k < 8; ++k) {
        float wy = (float)((tm[k] >> 16) & 0xffu) * (1.0f / 255.0f);
        float wx = (float)(tm[k] >> 24)           * (1.0f / 255.0f);
        HCV c0, c1;
        c0.u = glo[k]; c1.u = ghi[k];
        float g00 = (float)c0.h[0], g01 = (float)c0.h[1];
        float g10 = (float)c1.h[0], g11 = (float)c1.h[1];
        float top = fmaf(wx, g01 - g00, g00);
        float bot = fmaf(wx, g11 - g10, g10);
        acc = fmaf(aff[k], fmaf(wy, bot - top, top), acc);
    }

    // ---- phase D: store ----
    float feat = (dd > 0.f) ? dd : acc;
    if (LAST) {
        out[p] = feat;
    } else {
        _Float16 o = (_Float16)(feat * cf);
        _Float16* O0b = O0 + (size_t)b * PP;
        _Float16* O1b = O1 + (size_t)b * PP;
        O0b[bp]     = o;
        O1b[bp - 1] = o;
    }
}

// ---------------------------------------------------------------------------
// fallback (round-1 style) if workspace is too small
// ---------------------------------------------------------------------------
__global__ __launch_bounds__(256) void nlspn_init_kernel(
    const float* __restrict__ pred,
    const float* __restrict__ conf,
    float* __restrict__ ff)
{
    int p = blockIdx.x * blockDim.x + threadIdx.x;
    if (p < NPIX) ff[p] = pred[p] * conf[p];
}

template <bool LAST>
__global__ __launch_bounds__(256) void nlspn_prop_kernel(
    const float* __restrict__ aff_raw,
    const float* __restrict__ offset,
    const float* __restrict__ conf,
    const float* __restrict__ dep,
    const float* __restrict__ scale,
    const float* __restrict__ ff_in,
    float* __restrict__ out)
{
    int p = blockIdx.x * blockDim.x + threadIdx.x;
    if (p >= NPIX) return;
    int b  = p / HWN;
    int hw = p - b * HWN;
    int h  = hw / WNUM;
    int w  = hw - h * WNUM;

    float s    = scale[0];
    float invs = 1.0f / (s + 1e-8f);

    float a[8];
    const float* ar = aff_raw + (size_t)b * 8 * HWN + hw;
#pragma unroll
    for (int k = 0; k < 8; ++k) a[k] = ar[(size_t)k * HWN];

    float asum = 0.0f;
#pragma unroll
    for (int k = 0; k < 8; ++k) {
        a[k] = fast_tanh(a[k]) * invs;
        asum += fabsf(a[k]);
    }
    asum += 1e-4f;
    float rden = 1.0f / fmaxf(asum, 1.0f);
    float suma = 0.0f;
#pragma unroll
    for (int k = 0; k < 8; ++k) { a[k] *= rden; suma += a[k]; }
    float aref = 1.0f - suma;

    const float* ffb = ff_in + (size_t)b * HWN;
    float acc = aref * ffb[hw];

    const float* off = offset + (size_t)b * 16 * HWN + hw;
#pragma unroll
    for (int k = 0; k < 8; ++k) {
        int   k9 = (k < 4) ? k : k + 1;
        int   dy = k9 / 3 - 1;
        int   dx = k9 - (k9 / 3) * 3 - 1;
        float offy = off[(size_t)(2 * k)     * HWN];
        float offx = off[(size_t)(2 * k + 1) * HWN];
        float ysf = (float)(h + dy) + offy;
        float xsf = (float)(w + dx) + offx;
        float y0f = floorf(ysf);
        float x0f = floorf(xsf);
        float wy  = ysf - y0f;
        float wx  = xsf - x0f;
        int   y0  = (int)y0f;
        int   x0  = (int)x0f;
        bool yv0 = (y0 >= 0)  & (y0 < HNUM);
        bool yv1 = (y0 >= -1) & (y0 + 1 < HNUM);
        bool xv0 = (x0 >= 0)  & (x0 < WNUM);
        bool xv1 = (x0 >= -1) & (x0 + 1 < WNUM);
        int row0 = y0 * WNUM;
        float g00 = 0.f, g01 = 0.f, g10 = 0.f, g11 = 0.f;
        if (yv0 & xv0) g00 = ffb[row0 + x0];
        if (yv0 & xv1) g01 = ffb[row0 + x0 + 1];
        if (yv1 & xv0) g10 = ffb[row0 + WNUM + x0];
        if (yv1 & xv1) g11 = ffb[row0 + WNUM + x0 + 1];
        float sampled = (1.f - wy) * ((1.f - wx) * g00 + wx * g01)
                      +        wy  * ((1.f - wx) * g10 + wx * g11);
        acc += a[k] * sampled;
    }

    float dd   = dep[p];
    float feat = (dd > 0.0f) ? dd : acc;
    if (LAST) out[p] = feat;
    else      out[p] = feat * conf[p];
}

// ---------------------------------------------------------------------------
extern "C" void kernel_launch(void* const* d_in, const int* in_sizes, int n_in,
                              void* d_out, int out_size, void* d_ws, size_t ws_size,
                              hipStream_t stream)
{
    const float* aff_raw = (const float*)d_in[0];
    const float* offset  = (const float*)d_in[1];
    const float* conf    = (const float*)d_in[2];
    const float* pred    = (const float*)d_in[3];
    const float* dep     = (const float*)d_in[4];
    const float* scale   = (const float*)d_in[5];
    float* out = (float*)d_out;

    const int threads = 256;
    const int blocksP = (NPIX + threads - 1) / threads;
    const int blocksI = (NPP + threads - 1) / threads;

    const size_t need = (size_t)NPIX * 56 + (size_t)NPP * 2 * 4 + 64;

    if (ws_size >= need) {
        char* wb = (char*)d_ws;
        uint4* tapsA = (uint4*)wb;  wb += (size_t)NPIX * 16;
        uint4* tapsB = (uint4*)wb;  wb += (size_t)NPIX * 16;
        uint4* affv  = (uint4*)wb;  wb += (size_t)NPIX * 16;
        uint2* auxv  = (uint2*)wb;  wb += (size_t)NPIX * 8;
        _Float16* A0 = (_Float16*)wb;  wb += (size_t)NPP * 2;
        _Float16* A1 = (_Float16*)wb;  wb += (size_t)NPP * 2;
        _Float16* B0 = (_Float16*)wb;  wb += (size_t)NPP * 2;
        _Float16* B1 = (_Float16*)wb;

        nlspn_init_dual<<<blocksI, threads, 0, stream>>>(pred, conf, A0, A1, B0, B1);
        nlspn_step1_build<<<GRIDP, threads, 0, stream>>>(
            aff_raw, offset, conf, dep, scale, A0, A1, B0, B1,
            tapsA, tapsB, affv, auxv);                                      // ff1 -> B
        nlspn_prop_dual<false><<<GRIDP, threads, 0, stream>>>(
            tapsA, tapsB, affv, auxv, B0, B1, A0, A1, out);                 // ff2 -> A
        nlspn_prop_dual<false><<<GRIDP, threads, 0, stream>>>(
            tapsA, tapsB, affv, auxv, A0, A1, B0, B1, out);                 // ff3 -> B
        nlspn_prop_dual<false><<<GRIDP, threads, 0, stream>>>(
            tapsA, tapsB, affv, auxv, B0, B1, A0, A1, out);                 // ff4 -> A
        nlspn_prop_dual<false><<<GRIDP, threads, 0, stream>>>(
            tapsA, tapsB, affv, auxv, A0, A1, B0, B1, out);                 // ff5 -> B
        nlspn_prop_dual<true><<<GRIDP, threads, 0, stream>>>(
            tapsA, tapsB, affv, auxv, B0, B1, A0, A1, out);                 // feat6 -> d_out
    } else {
        float* ws = (float*)d_ws;
        nlspn_init_kernel<<<blocksP, threads, 0, stream>>>(pred, conf, out);
        nlspn_prop_kernel<false><<<blocksP, threads, 0, stream>>>(aff_raw, offset, conf, dep, scale, out, ws);
        nlspn_prop_kernel<false><<<blocksP, threads, 0, stream>>>(aff_raw, offset, conf, dep, scale, ws, out);
        nlspn_prop_kernel<false><<<blocksP, threads, 0, stream>>>(aff_raw, offset, conf, dep, scale, out, ws);
        nlspn_prop_kernel<false><<<blocksP, threads, 0, stream>>>(aff_raw, offset, conf, dep, scale, ws, out);
        nlspn_prop_kernel<false><<<blocksP, threads, 0, stream>>>(aff_raw, offset, conf, dep, scale, out, ws);
        nlspn_prop_kernel<true ><<<blocksP, threads, 0, stream>>>(aff_raw, offset, conf, dep, scale, ws, out);
    }
}

// Round 11
// 121.362 us; speedup vs baseline: 9.2272x; 1.2777x over previous
//
#include <hip/hip_runtime.h>
#include <stdint.h>

#define HNUM 240
#define WNUM 1216
#define BNUM 4
#define HWN (HNUM * WNUM)
#define NPIX (BNUM * HWN)

#define TR 16                 /* tile rows */
#define TC 64                 /* tile cols */
#define RH 12                 /* halo radius */
#define LR (TR + 2 * RH + 1)  /* 41 LDS rows */
#define LC (TC + 2 * RH + 1)  /* 89 LDS cols used */
#define LCP 90                /* LDS col stride (banks spread) */
#define LDSN (LR * LCP)       /* 3690 */
#define PXJ 4                 /* px per thread */
#define TGR (HNUM / TR)       /* 15 */
#define TGC (WNUM / TC)       /* 19 */
#define NTILE (BNUM * TGR * TGC)  /* 1140 blocks */

union HCV { uint32_t u; _Float16 h[2]; };

__device__ __forceinline__ float fast_tanh(float x) {
    float ax = fabsf(x);
    float e  = __builtin_amdgcn_exp2f(ax * 2.885390081777927f);  // 2*log2(e)
    float t  = 1.0f - 2.0f * __builtin_amdgcn_rcpf(e + 1.0f);
    return copysignf(t, x);
}

// ---------------------------------------------------------------------------
// step 1 fused with meta build. Tile 16x64, halo 12, pred*conf staged in LDS.
// meta/px: 8 taps u32 (drow s8 | dcol s8 | qy u8 | qx u8) in tapsA/tapsB,
//          affaux u4 = {affs s8 x4, affs s8 x4, (aref|conf) fp16x2, dep f32}
// ---------------------------------------------------------------------------
__global__ __launch_bounds__(256) void nlspn_step1_lds(
    const float* __restrict__ aff_raw,
    const float* __restrict__ offset,
    const float* __restrict__ conf,
    const float* __restrict__ dep,
    const float* __restrict__ pred,
    const float* __restrict__ scale,
    _Float16* __restrict__ planeOut,
    uint4* __restrict__ tapsA,
    uint4* __restrict__ tapsB,
    uint4* __restrict__ affaux)
{
    __shared__ _Float16 tile[LDSN];

    int bid  = blockIdx.x;
    int b    = bid / (TGR * TGC);
    int rem  = bid - b * (TGR * TGC);
    int tr   = rem / TGC;
    int tc   = rem - tr * TGC;
    int tid  = (int)threadIdx.x;
    int lane = tid & 63;
    int wrow = tid >> 6;

    int row0 = tr * TR - RH;
    int col0 = tc * TC - RH;

    // ---- stage ff0 = pred*conf (zero outside image) ----
    for (int i = tid; i < LDSN; i += 256) {
        int lr = i / LCP;
        int lc = i - lr * LCP;
        int gr = row0 + lr;
        int gc = col0 + lc;
        float v = 0.f;
        if (lc < LC && gr >= 0 && gr < HNUM && gc >= 0 && gc < WNUM) {
            int pi = b * HWN + gr * WNUM + gc;
            v = pred[pi] * conf[pi];
        }
        tile[i] = (_Float16)v;
    }
    __syncthreads();

    float s    = scale[0];
    float invs = 1.0f / (s + 1e-8f);

#pragma unroll
    for (int j = 0; j < PXJ; ++j) {
        int rj = wrow * PXJ + j;
        int h  = tr * TR + rj;
        int w  = tc * TC + lane;
        int hw = h * WNUM + w;
        int p  = b * HWN + hw;

        // affinity normalization
        const float* arb = aff_raw + (size_t)b * 8 * HWN + hw;
        float aa[8];
        float asum = 0.f;
#pragma unroll
        for (int k = 0; k < 8; ++k) {
            float t = fast_tanh(arb[(size_t)k * HWN]) * invs;
            aa[k] = t;
            asum += fabsf(t);
        }
        float rden = 1.0f / fmaxf(asum + 1e-4f, 1.0f);
        float sm = 0.f;
#pragma unroll
        for (int k = 0; k < 8; ++k) { aa[k] *= rden; sm += aa[k]; }
        float aref = 1.0f - sm;

        // build taps + gather from LDS
        int cbase = (RH + rj) * LCP + (RH + lane);
        float acc = aref * (float)tile[cbase];

        const float* ofb = offset + (size_t)b * 16 * HWN + hw;
        uint32_t tw[8];
#pragma unroll
        for (int k = 0; k < 8; ++k) {
            int k9 = (k < 4) ? k : k + 1;
            int dy = k9 / 3 - 1;
            int dx = k9 - (k9 / 3) * 3 - 1;
            float offy = ofb[(size_t)(2 * k)     * HWN];
            float offx = ofb[(size_t)(2 * k + 1) * HWN];
            float ys  = (float)(h + dy) + offy;
            float xs  = (float)(w + dx) + offx;
            float y0f = floorf(ys), x0f = floorf(xs);
            float wyf = ys - y0f,   wxf = xs - x0f;
            int drow = (int)y0f - h;
            int dcol = (int)x0f - w;
            uint32_t qy = (uint32_t)(wyf * 255.0f + 0.5f); if (qy > 255) qy = 255;
            uint32_t qx = (uint32_t)(wxf * 255.0f + 0.5f); if (qx > 255) qx = 255;
            int lr = RH + rj + drow;
            int lc = RH + lane + dcol;
            if (lr < 0 || lr > LR - 2 || lc < 0 || lc > LC - 2) {
                drow = 0; dcol = 0; qy = 0; qx = 0; aa[k] = 0.f;
            }
            tw[k] = (uint32_t)(uint8_t)(int8_t)drow
                  | ((uint32_t)(uint8_t)(int8_t)dcol << 8)
                  | (qy << 16) | (qx << 24);

            int la = cbase + drow * LCP + dcol;
            float g00 = (float)tile[la];
            float g01 = (float)tile[la + 1];
            float g10 = (float)tile[la + LCP];
            float g11 = (float)tile[la + LCP + 1];
            float fwy = (float)qy * (1.0f / 255.0f);
            float fwx = (float)qx * (1.0f / 255.0f);
            float top = fmaf(fwx, g01 - g00, g00);
            float bot = fmaf(fwx, g11 - g10, g10);
            acc = fmaf(aa[k], fmaf(fwy, bot - top, top), acc);
        }

        tapsA[p] = make_uint4(tw[0], tw[1], tw[2], tw[3]);
        tapsB[p] = make_uint4(tw[4], tw[5], tw[6], tw[7]);

        // quantize affs to s8
        uint32_t pk[2] = {0u, 0u};
#pragma unroll
        for (int k = 0; k < 8; ++k) {
            int q = (int)floorf(aa[k] * 127.0f + 0.5f);
            q = (q < -127) ? -127 : ((q > 127) ? 127 : q);
            pk[k >> 2] |= ((uint32_t)(uint8_t)(int8_t)q) << (8 * (k & 3));
        }
        float cf = conf[p];
        float dd = dep[p];
        HCV cv;
        cv.h[0] = (_Float16)aref;
        cv.h[1] = (_Float16)cf;
        affaux[p] = make_uint4(pk[0], pk[1], cv.u, __float_as_uint(dd));

        float feat = (dd > 0.f) ? dd : acc;
        planeOut[p] = (_Float16)(feat * cf);
    }
}

// ---------------------------------------------------------------------------
// propagation step: stage plane tile in LDS, 33 LDS gathers/px, meta streamed
// ---------------------------------------------------------------------------
template <bool LAST>
__global__ __launch_bounds__(256) void nlspn_prop_lds(
    const uint4* __restrict__ tapsA,
    const uint4* __restrict__ tapsB,
    const uint4* __restrict__ affaux,
    const _Float16* __restrict__ planeIn,
    _Float16* __restrict__ planeOut,
    float* __restrict__ out)
{
    __shared__ _Float16 tile[LDSN];

    int bid  = blockIdx.x;
    int b    = bid / (TGR * TGC);
    int rem  = bid - b * (TGR * TGC);
    int tr   = rem / TGC;
    int tc   = rem - tr * TGC;
    int tid  = (int)threadIdx.x;
    int lane = tid & 63;
    int wrow = tid >> 6;

    int row0 = tr * TR - RH;
    int col0 = tc * TC - RH;
    const _Float16* pb = planeIn + (size_t)b * HWN;

    for (int i = tid; i < LDSN; i += 256) {
        int lr = i / LCP;
        int lc = i - lr * LCP;
        int gr = row0 + lr;
        int gc = col0 + lc;
        _Float16 v = (_Float16)0.f;
        if (lc < LC && gr >= 0 && gr < HNUM && gc >= 0 && gc < WNUM)
            v = pb[gr * WNUM + gc];
        tile[i] = v;
    }
    __syncthreads();

#pragma unroll
    for (int j = 0; j < PXJ; ++j) {
        int rj = wrow * PXJ + j;
        int h  = tr * TR + rj;
        int w  = tc * TC + lane;
        int p  = b * HWN + h * WNUM + w;

        uint4 tA = tapsA[p];
        uint4 tB = tapsB[p];
        uint4 ax = affaux[p];

        // decode affs (s8)
        float af[8];
        int32_t vx = (int32_t)ax.x;
        int32_t vy = (int32_t)ax.y;
        af[0] = (float)((vx << 24) >> 24) * (1.0f / 127.0f);
        af[1] = (float)((vx << 16) >> 24) * (1.0f / 127.0f);
        af[2] = (float)((vx <<  8) >> 24) * (1.0f / 127.0f);
        af[3] = (float)( vx        >> 24) * (1.0f / 127.0f);
        af[4] = (float)((vy << 24) >> 24) * (1.0f / 127.0f);
        af[5] = (float)((vy << 16) >> 24) * (1.0f / 127.0f);
        af[6] = (float)((vy <<  8) >> 24) * (1.0f / 127.0f);
        af[7] = (float)( vy        >> 24) * (1.0f / 127.0f);

        HCV cv; cv.u = ax.z;
        float aref = (float)cv.h[0];
        float cf   = (float)cv.h[1];
        float dd   = __uint_as_float(ax.w);

        int cbase = (RH + rj) * LCP + (RH + lane);
        float acc = aref * (float)tile[cbase];

        uint32_t tm[8] = {tA.x, tA.y, tA.z, tA.w, tB.x, tB.y, tB.z, tB.w};
#pragma unroll
        for (int k = 0; k < 8; ++k) {
            uint32_t m = tm[k];
            int drow = (int)(int8_t)(m & 0xffu);
            int dcol = (int)(int8_t)((m >> 8) & 0xffu);
            float wy = (float)((m >> 16) & 0xffu) * (1.0f / 255.0f);
            float wx = (float)(m >> 24)           * (1.0f / 255.0f);
            int la = cbase + drow * LCP + dcol;
            float g00 = (float)tile[la];
            float g01 = (float)tile[la + 1];
            float g10 = (float)tile[la + LCP];
            float g11 = (float)tile[la + LCP + 1];
            float top = fmaf(wx, g01 - g00, g00);
            float bot = fmaf(wx, g11 - g10, g10);
            acc = fmaf(af[k], fmaf(wy, bot - top, top), acc);
        }

        float feat = (dd > 0.f) ? dd : acc;
        if (LAST) out[p] = feat;
        else      planeOut[p] = (_Float16)(feat * cf);
    }
}

// ---------------------------------------------------------------------------
// fallback (round-1 style) if workspace is too small
// ---------------------------------------------------------------------------
__global__ __launch_bounds__(256) void nlspn_init_kernel(
    const float* __restrict__ pred,
    const float* __restrict__ conf,
    float* __restrict__ ff)
{
    int p = blockIdx.x * blockDim.x + threadIdx.x;
    if (p < NPIX) ff[p] = pred[p] * conf[p];
}

template <bool LAST>
__global__ __launch_bounds__(256) void nlspn_prop_kernel(
    const float* __restrict__ aff_raw,
    const float* __restrict__ offset,
    const float* __restrict__ conf,
    const float* __restrict__ dep,
    const float* __restrict__ scale,
    const float* __restrict__ ff_in,
    float* __restrict__ out)
{
    int p = blockIdx.x * blockDim.x + threadIdx.x;
    if (p >= NPIX) return;
    int b  = p / HWN;
    int hw = p - b * HWN;
    int h  = hw / WNUM;
    int w  = hw - h * WNUM;

    float s    = scale[0];
    float invs = 1.0f / (s + 1e-8f);

    float a[8];
    const float* ar = aff_raw + (size_t)b * 8 * HWN + hw;
#pragma unroll
    for (int k = 0; k < 8; ++k) a[k] = ar[(size_t)k * HWN];

    float asum = 0.0f;
#pragma unroll
    for (int k = 0; k < 8; ++k) {
        a[k] = fast_tanh(a[k]) * invs;
        asum += fabsf(a[k]);
    }
    asum += 1e-4f;
    float rden = 1.0f / fmaxf(asum, 1.0f);
    float suma = 0.0f;
#pragma unroll
    for (int k = 0; k < 8; ++k) { a[k] *= rden; suma += a[k]; }
    float aref = 1.0f - suma;

    const float* ffb = ff_in + (size_t)b * HWN;
    float acc = aref * ffb[hw];

    const float* off = offset + (size_t)b * 16 * HWN + hw;
#pragma unroll
    for (int k = 0; k < 8; ++k) {
        int   k9 = (k < 4) ? k : k + 1;
        int   dy = k9 / 3 - 1;
        int   dx = k9 - (k9 / 3) * 3 - 1;
        float offy = off[(size_t)(2 * k)     * HWN];
        float offx = off[(size_t)(2 * k + 1) * HWN];
        float ysf = (float)(h + dy) + offy;
        float xsf = (float)(w + dx) + offx;
        float y0f = floorf(ysf);
        float x0f = floorf(xsf);
        float wy  = ysf - y0f;
        float wx  = xsf - x0f;
        int   y0  = (int)y0f;
        int   x0  = (int)x0f;
        bool yv0 = (y0 >= 0)  & (y0 < HNUM);
        bool yv1 = (y0 >= -1) & (y0 + 1 < HNUM);
        bool xv0 = (x0 >= 0)  & (x0 < WNUM);
        bool xv1 = (x0 >= -1) & (x0 + 1 < WNUM);
        int row0 = y0 * WNUM;
        float g00 = 0.f, g01 = 0.f, g10 = 0.f, g11 = 0.f;
        if (yv0 & xv0) g00 = ffb[row0 + x0];
        if (yv0 & xv1) g01 = ffb[row0 + x0 + 1];
        if (yv1 & xv0) g10 = ffb[row0 + WNUM + x0];
        if (yv1 & xv1) g11 = ffb[row0 + WNUM + x0 + 1];
        float sampled = (1.f - wy) * ((1.f - wx) * g00 + wx * g01)
                      +        wy  * ((1.f - wx) * g10 + wx * g11);
        acc += a[k] * sampled;
    }

    float dd   = dep[p];
    float feat = (dd > 0.0f) ? dd : acc;
    if (LAST) out[p] = feat;
    else      out[p] = feat * conf[p];
}

// ---------------------------------------------------------------------------
extern "C" void kernel_launch(void* const* d_in, const int* in_sizes, int n_in,
                              void* d_out, int out_size, void* d_ws, size_t ws_size,
                              hipStream_t stream)
{
    const float* aff_raw = (const float*)d_in[0];
    const float* offset  = (const float*)d_in[1];
    const float* conf    = (const float*)d_in[2];
    const float* pred    = (const float*)d_in[3];
    const float* dep     = (const float*)d_in[4];
    const float* scale   = (const float*)d_in[5];
    float* out = (float*)d_out;

    const int threads = 256;
    const size_t need = (size_t)NPIX * 48 + (size_t)NPIX * 2 * 2 + 64;

    if (ws_size >= need) {
        char* wb = (char*)d_ws;
        uint4* tapsA  = (uint4*)wb;  wb += (size_t)NPIX * 16;
        uint4* tapsB  = (uint4*)wb;  wb += (size_t)NPIX * 16;
        uint4* affaux = (uint4*)wb;  wb += (size_t)NPIX * 16;
        _Float16* plA = (_Float16*)wb;  wb += (size_t)NPIX * 2;
        _Float16* plB = (_Float16*)wb;

        nlspn_step1_lds<<<NTILE, threads, 0, stream>>>(
            aff_raw, offset, conf, dep, pred, scale,
            plB, tapsA, tapsB, affaux);                                     // ff1 -> B
        nlspn_prop_lds<false><<<NTILE, threads, 0, stream>>>(
            tapsA, tapsB, affaux, plB, plA, out);                           // ff2 -> A
        nlspn_prop_lds<false><<<NTILE, threads, 0, stream>>>(
            tapsA, tapsB, affaux, plA, plB, out);                           // ff3 -> B
        nlspn_prop_lds<false><<<NTILE, threads, 0, stream>>>(
            tapsA, tapsB, affaux, plB, plA, out);                           // ff4 -> A
        nlspn_prop_lds<false><<<NTILE, threads, 0, stream>>>(
            tapsA, tapsB, affaux, plA, plB, out);                           // ff5 -> B
        nlspn_prop_lds<true><<<NTILE, threads, 0, stream>>>(
            tapsA, tapsB, affaux, plB, plA, out);                           // feat6 -> d_out
    } else {
        const int blocksP = (NPIX + threads - 1) / threads;
        float* ws = (float*)d_ws;
        nlspn_init_kernel<<<blocksP, threads, 0, stream>>>(pred, conf, out);
        nlspn_prop_kernel<false><<<blocksP, threads, 0, stream>>>(aff_raw, offset, conf, dep, scale, out, ws);
        nlspn_prop_kernel<false><<<blocksP, threads, 0, stream>>>(aff_raw, offset, conf, dep, scale, ws, out);
        nlspn_prop_kernel<false><<<blocksP, threads, 0, stream>>>(aff_raw, offset, conf, dep, scale, out, ws);
        nlspn_prop_kernel<false><<<blocksP, threads, 0, stream>>>(aff_raw, offset, conf, dep, scale, ws, out);
        nlspn_prop_kernel<false><<<blocksP, threads, 0, stream>>>(aff_raw, offset, conf, dep, scale, out, ws);
        nlspn_prop_kernel<true ><<<blocksP, threads, 0, stream>>>(aff_raw, offset, conf, dep, scale, ws, out);
    }
}